// Round 17
// baseline (320.860 us; speedup 1.0000x reference)
//
#include <hip/hip_runtime.h>
#include <stdint.h>

#define NPIX 1024
#define NEDGE 1984
#define NSORT 2048
#define CROWS 64          // replay label rows (4 waves x 16)
#define CNTW (NPIX + 2)   // pad rows (even): replay lanes hit distinct banks; u32-aligned

// ---- d_ws layout (~4.73 MB) ----
#define WS_PART   0u          // f64[256]   per-task loss partials
#define WS_SKIP   2048u       // u32[64]    per-window skip flag
#define WS_NLAB   2304u       // u32[128]   per (bat,win) active-label count
#define WS_M      2816u       // u32[256]   per-task record count
#define WS_PW     4096u       // f32[128*1024]
#define WS_LAB    528384u     // u16[128*1024]  CC labels (min-pixel-id+1, 0=bg)
#define WS_LABD   790528u     // u16[128*1024]  active dense id+1 at min pixel
#define WS_REC    1052672u    // u32[256*1024]  packed e(11)|ra(10)|rb(10)
#define WS_ORD    2101248u    // u16[256*2048]  sorted edge order per task
#define WS_MSNAP  3149824u    // u32[256*3]     record counts at snapshots
#define WS_SNAP   3153920u    // u16[256*3*1024] resolved roots at snapshots

__device__ __forceinline__ void edge_nodes(int e, int& a, int& b) {
  if (e < 992) { int r = e / 31; int c = e - r * 31; a = (r << 5) + c; b = a + 1; }
  else         { a = e - 992; b = a + 32; }
}

// u16 counter increment via aligned u32 atomic (halves < 65536: no carry)
__device__ __forceinline__ void cinc(uint16_t* row, int root) {
  uint32_t* w = (uint32_t*)(row + (root & ~1));
  atomicAdd(w, (root & 1) ? 0x10000u : 1u);
}

// path-halving find; concurrent halving writes are ancestor-monotone (safe)
__device__ __forceinline__ int uf_find(volatile uint32_t* par, int x) {
  int p = (int)par[x];
  while (p != x) {
    int gp = (int)par[p];
    par[x] = (uint32_t)gp;
    x = gp; p = (int)par[x];
  }
  return x;
}

// union-by-min with CAS hooking (Playne-Stephens style): final root = min id
__device__ __forceinline__ void uf_union(volatile uint32_t* par, int a, int b) {
  int ra = uf_find(par, a), rb = uf_find(par, b);
  while (ra != rb) {
    if (ra > rb) { int t2 = ra; ra = rb; rb = t2; }
    unsigned old = atomicCAS((unsigned*)(par + rb), (unsigned)rb, (unsigned)ra);
    if (old == (unsigned)rb) break;
    rb = uf_find(par, (int)old);
    ra = uf_find(par, ra);
  }
}

// ============ K1: load + skip predicate + union-find CC + label census ============
__global__ __launch_bounds__(256) void k1_prep(const float* __restrict__ y_true,
                                               const float* __restrict__ y_pred,
                                               char* __restrict__ ws) {
  __shared__ float    Pw[NPIX];
  __shared__ uint16_t lab[NPIX];
  __shared__ uint8_t  maskv[NPIX];
  __shared__ uint32_t lcnt[NPIX];
  __shared__ uint32_t par32[NPIX];
  __shared__ unsigned minP, maxP, minT, maxT;
  __shared__ int nl;
  const int tid = threadIdx.x, pw = blockIdx.x, bat = pw >> 6, win = pw & 63;
  const int wr = win >> 3, wc = win & 7;
  if (tid == 0) { minP = ~0u; maxP = 0u; minT = ~0u; maxT = 0u; nl = 0; }
  __syncthreads();
  {
    unsigned mnP = ~0u, mxP = 0u, mnT = ~0u, mxT = 0u;
    for (int i = tid; i < 2 * NPIX; i += 256) {
      int bb = i >> 10, p = i & (NPIX - 1);
      int r = p >> 5, c = p & 31;
      size_t g = ((size_t)(bb * 256 + wr * 32 + r)) * 256 + (size_t)(wc * 32 + c);
      float pv = y_pred[g], tv = y_true[g];
      unsigned pu = __float_as_uint(pv), tu = __float_as_uint(tv);
      mnP = min(mnP, pu); mxP = max(mxP, pu);
      mnT = min(mnT, tu); mxT = max(mxT, tu);
      if (bb == bat) {
        Pw[p] = pv; maskv[p] = (tv == 0.f) ? 1 : 0;
        par32[p] = (uint32_t)p;
        lcnt[p] = 0u;
      }
    }
    atomicMin(&minP, mnP); atomicMax(&maxP, mxP);   // valid: values >= 0
    atomicMin(&minT, mnT); atomicMax(&maxT, mxT);
  }
  __syncthreads();
  {
    float a = __uint_as_float(minP), b = __uint_as_float(maxP);
    float c2 = __uint_as_float(minT), d = __uint_as_float(maxT);
    int skip = (a == 1.f || b == 0.f || c2 == 1.f || d == 0.f) ? 1 : 0;
    if (tid == 0) ((uint32_t*)(ws + WS_SKIP))[win] = (uint32_t)skip;  // dup write: same value
    if (skip) return;
  }
  // ---- 8-connected CC: single edge pass, atomic union-by-min in LDS
  for (int p = tid; p < NPIX; p += 256) {
    if (!maskv[p]) continue;
    int r = p >> 5, c = p & 31;
    if (c < 31 && maskv[p + 1]) uf_union(par32, p, p + 1);
    if (r < 31) {
      if (maskv[p + 32])           uf_union(par32, p, p + 32);
      if (c < 31 && maskv[p + 33]) uf_union(par32, p, p + 33);
      if (c > 0  && maskv[p + 31]) uf_union(par32, p, p + 31);
    }
  }
  __syncthreads();
  // resolve roots (read-only walk; all unions complete) -> lab = min id + 1
  for (int p = tid; p < NPIX; p += 256) {
    uint16_t l = 0;
    if (maskv[p]) {
      int x = p, px = (int)par32[x];
      while (px != x) { x = px; px = (int)par32[x]; }
      l = (uint16_t)(x + 1);
    }
    lab[p] = l;
  }
  __syncthreads();
  for (int p = tid; p < NPIX; p += 256)
    if (maskv[p]) atomicAdd(&lcnt[lab[p] - 1], 1u);
  __syncthreads();
  uint16_t* labDG = (uint16_t*)(ws + WS_LABD) + (size_t)pw * NPIX;
  for (int p = tid; p < NPIX; p += 256) {
    uint16_t v = 0;
    if (maskv[p] && lab[p] == (uint16_t)(p + 1) && lcnt[p] >= 2u)
      v = (uint16_t)(atomicAdd(&nl, 1) + 1);
    labDG[p] = v;
  }
  __syncthreads();
  float*    PwG  = (float*)(ws + WS_PW)  + (size_t)pw * NPIX;
  uint16_t* labG = (uint16_t*)(ws + WS_LAB) + (size_t)pw * NPIX;
  for (int p = tid; p < NPIX; p += 256) { PwG[p] = Pw[p]; labG[p] = lab[p]; }
  if (tid == 0) ((uint32_t*)(ws + WS_NLAB))[pw] = (uint32_t)nl;
}

// ============ K2a: edge keys + register-fused bitonic sort -> order to ws ============
__global__ __launch_bounds__(256) void k2a_sort(char* __restrict__ ws) {
  __shared__ unsigned long long keys[NSORT];   // 16 KB
  __shared__ float    Pw[NPIX];
  __shared__ uint16_t lab[NPIX];
  const int tid = threadIdx.x, t = blockIdx.x;
  const int sign = t & 1, win = (t >> 1) & 63, bat = t >> 7;
  const int pw = bat * 64 + win;
  if (((const uint32_t*)(ws + WS_SKIP))[win]) return;
  const float*    PwG  = (const float*)(ws + WS_PW)  + (size_t)pw * NPIX;
  const uint16_t* labG = (const uint16_t*)(ws + WS_LAB) + (size_t)pw * NPIX;
  for (int p = tid; p < NPIX; p += 256) { Pw[p] = PwG[p]; lab[p] = labG[p]; }
  __syncthreads();
  for (int e = tid; e < NSORT; e += 256) {
    if (e < NEDGE) {
      int a, b; edge_nodes(e, a, b);
      int cls = (lab[a] ? 0 : 1) + (lab[b] ? 0 : 1);
      float cost = Pw[a] + Pw[b];
      if (sign == 0) { if (cls == 2) cost = 20.0f; }   // costs_n[gt>20]=20
      else           { if (cls == 0) cost = 0.0f;  }   // costs_p[gt<10]=0
      keys[e] = (((unsigned long long)(__float_as_uint(cost) ^ 0xFFFFFFFFu)) << 32)
                | (unsigned long long)(unsigned)e;
    } else keys[e] = ~0ull;
  }
  __syncthreads();
  // register-fused bitonic (proven R7-R16)
  {
    unsigned long long x[8];
    const int baseI = tid * 8;
    #pragma unroll
    for (int v = 0; v < 8; ++v) x[v] = keys[baseI + v];
    #pragma unroll
    for (int kk = 2; kk <= 8; kk <<= 1) {
      #pragma unroll
      for (int j = kk >> 1; j > 0; j >>= 1) {
        #pragma unroll
        for (int v = 0; v < 8; ++v) {
          int p = v ^ j;
          if (p > v) {
            bool asc = (((baseI + v) & kk) == 0);
            unsigned long long A = x[v], B = x[p];
            if ((A > B) == asc) { x[v] = B; x[p] = A; }
          }
        }
      }
    }
    #pragma unroll
    for (int v = 0; v < 8; ++v) keys[baseI + v] = x[v];
  }
  for (int k = 16; k <= NSORT; k <<= 1) {
    for (int j = k >> 1; j >= 8; j >>= 1) {
      __syncthreads();
      for (int q = tid; q < NSORT / 2; q += 256) {
        int i = ((q & ~(j - 1)) << 1) | (q & (j - 1));
        int p = i + j;
        bool asc = ((i & k) == 0);
        unsigned long long A = keys[i], B = keys[p];
        if ((A > B) == asc) { keys[i] = B; keys[p] = A; }
      }
    }
    __syncthreads();
    {
      unsigned long long x[8];
      const int baseI = tid * 8;
      const bool asc = ((baseI & k) == 0);
      #pragma unroll
      for (int v = 0; v < 8; ++v) x[v] = keys[baseI + v];
      #pragma unroll
      for (int j = 4; j > 0; j >>= 1) {
        #pragma unroll
        for (int v = 0; v < 8; ++v) {
          int p = v ^ j;
          if (p > v) {
            unsigned long long A = x[v], B = x[p];
            if ((A > B) == asc) { x[v] = B; x[p] = A; }
          }
        }
      }
      #pragma unroll
      for (int v = 0; v < 8; ++v) keys[baseI + v] = x[v];
    }
  }
  __syncthreads();
  uint16_t* ordG = (uint16_t*)(ws + WS_ORD) + (size_t)t * NSORT;
  for (int i = tid; i < NSORT; i += 256) ordG[i] = (uint16_t)((unsigned)keys[i]);
}

// ============ K2b: register-UF wave Kruskal (group-of-4 serial core) ============
__global__ __launch_bounds__(256) void k2b_kruskal(char* __restrict__ ws) {
  __shared__ uint16_t par[NPIX];
  const int tid = threadIdx.x, t = blockIdx.x;
  const int win = (t >> 1) & 63;
  uint32_t* MG = (uint32_t*)(ws + WS_M);
  uint32_t* msW = (uint32_t*)(ws + WS_MSNAP) + t * 3;
  if (((const uint32_t*)(ws + WS_SKIP))[win]) { if (tid == 0) MG[t] = 0u; return; }
  for (int p = tid; p < NPIX; p += 256) par[p] = (uint16_t)p;
  __syncthreads();
  // wave 0 only. Serial resolution processes candidates in GROUPS OF 4:
  // extract 4 indices (SALU, mask fixed at batch start), 8 parallel readlanes,
  // scalar sequential resolve (chase = apply earlier group merges in order;
  // absorbed roots distinct -> composition exact), one fused 8-cndmask rename
  // chain, scalar parking targets. Amortizes SALU<->VALU round-trips 4x.
  // All cross-lane ops in wave-uniform control flow (CDNA exec-mask rule).
  if (tid < 64) {
    const int lane = tid;
    const uint16_t* ordG = (const uint16_t*)(ws + WS_ORD) + (size_t)t * NSORT;
    uint32_t* recG = (uint32_t*)(ws + WS_REC) + (size_t)t * NPIX;
    uint16_t* snapW = (uint16_t*)(ws + WS_SNAP) + (size_t)t * 3072;
    int mTotal = 0, nsnp = 0;
    unsigned eCur = (unsigned)ordG[lane];              // batch-0 prefetch
    for (int base = 0; base < NEDGE; base += 64) {
      unsigned e = eCur;
      if (base + 64 < NEDGE) eCur = (unsigned)ordG[base + 64 + lane];  // hide next load
      int a, b; edge_nodes((int)e, a, b);
      int xa = a, xb = b;
      for (;;) {
        int pa = par[xa], pb = par[xb];    // read-only dual walk
        if (pa == xa && pb == xb) break;
        xa = pa; xb = pb;
      }
      int ra = xa, rb = xb;
      bool cand0 = (ra != rb);
      // consecutive-duplicate pre-filter (R15): identical batch-start pair on
      // the previous lane -> provably rejected later; drop up front.
      unsigned pkMe = (unsigned)ra | ((unsigned)rb << 10) | (cand0 ? (1u << 20) : 0u);
      unsigned pkPrev = (unsigned)__shfl((int)pkMe, (lane + 63) & 63, 64);
      bool cand = cand0 && !((lane > 0) && (pkPrev == pkMe));
      unsigned long long cm = __ballot(cand);
      int mb = 0;
      unsigned recP = 0u;                   // lane-t_k packed (i | rA<<11 | rB<<21)
      while (cm) {
        // extract up to 4 candidate indices (independent of renames)
        int i0 = __ffsll((long long)cm) - 1; cm &= cm - 1;
        int n = 1, i1 = i0, i2 = i0, i3 = i0;
        if (cm) { i1 = __ffsll((long long)cm) - 1; cm &= cm - 1; n = 2;
          if (cm) { i2 = __ffsll((long long)cm) - 1; cm &= cm - 1; n = 3;
            if (cm) { i3 = __ffsll((long long)cm) - 1; cm &= cm - 1; n = 4; } } }
        // 8 parallel readlanes (group-start roots)
        int A0 = __builtin_amdgcn_readlane(ra, i0), B0 = __builtin_amdgcn_readlane(rb, i0);
        int A1 = __builtin_amdgcn_readlane(ra, i1), B1 = __builtin_amdgcn_readlane(rb, i1);
        int A2 = __builtin_amdgcn_readlane(ra, i2), B2 = __builtin_amdgcn_readlane(rb, i2);
        int A3 = __builtin_amdgcn_readlane(ra, i3), B3 = __builtin_amdgcn_readlane(rb, i3);
        // scalar sequential resolve in reference order
        bool a0 = (A0 != B0);
        int sB0 = a0 ? B0 : -1;             // sentinel -1: no root matches
        if (A1 == sB0) A1 = A0;  if (B1 == sB0) B1 = A0;
        bool a1 = (n > 1) && (A1 != B1);
        int sB1 = a1 ? B1 : -1;
        if (A2 == sB0) A2 = A0;  if (B2 == sB0) B2 = A0;
        if (A2 == sB1) A2 = A1;  if (B2 == sB1) B2 = A1;
        bool a2 = (n > 2) && (A2 != B2);
        int sB2 = a2 ? B2 : -1;
        if (A3 == sB0) A3 = A0;  if (B3 == sB0) B3 = A0;
        if (A3 == sB1) A3 = A1;  if (B3 == sB1) B3 = A1;
        if (A3 == sB2) A3 = A2;  if (B3 == sB2) B3 = A2;
        bool a3 = (n > 3) && (A3 != B3);
        int sB3 = a3 ? B3 : -1;
        // parking targets (scalar prefix)
        int t0 = mb;
        int t1 = t0 + (a0 ? 1 : 0);
        int t2 = t1 + (a1 ? 1 : 0);
        int t3 = t2 + (a2 ? 1 : 0);
        mb = t3 + (a3 ? 1 : 0);
        // park records (off the rename chain)
        if (a0 && lane == t0) recP = (unsigned)i0 | ((unsigned)A0 << 11) | ((unsigned)B0 << 21);
        if (a1 && lane == t1) recP = (unsigned)i1 | ((unsigned)A1 << 11) | ((unsigned)B1 << 21);
        if (a2 && lane == t2) recP = (unsigned)i2 | ((unsigned)A2 << 11) | ((unsigned)B2 << 21);
        if (a3 && lane == t3) recP = (unsigned)i3 | ((unsigned)A3 << 11) | ((unsigned)B3 << 21);
        // fused vector renames, reference order (sentinels disable rejected)
        ra = (ra == sB0) ? A0 : ra;  rb = (rb == sB0) ? A0 : rb;
        ra = (ra == sB1) ? A1 : ra;  rb = (rb == sB1) ? A1 : rb;
        ra = (ra == sB2) ? A2 : ra;  rb = (rb == sB2) ? A2 : rb;
        ra = (ra == sB3) ? A3 : ra;  rb = (rb == sB3) ? A3 : rb;
      }
      // end-of-batch: recover edge ids in parallel (one bpermute), write out
      unsigned eRec = (unsigned)__shfl((int)e, (int)(recP & 63u), 64);  // uniform flow
      if (lane < mb) {
        int rAo = (int)((recP >> 11) & 1023u);
        int rBo = (int)(recP >> 21);
        par[rBo] = (uint16_t)rAo;           // reference orientation par[rB]=rA
        recG[mTotal + lane] = (recP & 0xFFFFF800u) | eRec;
      }
      mTotal += mb;
      // batched pointer-jump compression (skip when chains are short)
      if (mb > 2 && (base + 64 < NEDGE)) {
        for (int pass = 0; pass < 2; ++pass) {
          uint16_t vv[16];
          #pragma unroll
          for (int j = 0; j < 16; ++j) vv[j] = par[j * 64 + lane];
          #pragma unroll
          for (int j = 0; j < 16; ++j) vv[j] = par[vv[j]];
          #pragma unroll
          for (int j = 0; j < 16; ++j) par[j * 64 + lane] = vv[j];
        }
      }
      // snapshot: fully-resolved roots once record count crosses s*256
      while (nsnp < 3 && mTotal >= 256 * (nsnp + 1)) {
        #pragma unroll
        for (int j = 0; j < 16; ++j) {
          int p = j * 64 + lane;
          int r = par[p], pr = par[r];
          while (pr != r) { r = pr; pr = par[r]; }
          snapW[nsnp * 1024 + p] = (uint16_t)r;
        }
        if (lane == 0) msW[nsnp] = (uint32_t)mTotal;
        ++nsnp;
      }
    }
    while (nsnp < 3) { if (lane == 0) msW[nsnp] = (uint32_t)mTotal; ++nsnp; }
    if (lane == 0) MG[t] = (uint32_t)mTotal;
  }
}

// ============ K2c: segment-parallel replay (4 waves over record segments) ============
__global__ __launch_bounds__(256) void k2c_replay(char* __restrict__ ws) {
  __shared__ union {
    uint16_t cnt[CROWS][CNTW];          // 131328 B (replay)
    double   red[256];                  //   2048 B (final reduction)
  } u;
  __shared__ float    Pw[NPIX];
  __shared__ uint16_t lab[NPIX];
  __shared__ uint16_t labD[NPIX];
  __shared__ uint32_t recW[NPIX];
  __shared__ uint32_t totp[NPIX];
  __shared__ uint32_t same[NPIX];
  __shared__ unsigned Ssum;
  const int tid = threadIdx.x, t = blockIdx.x;
  const int sign = t & 1, win = (t >> 1) & 63, bat = t >> 7;
  const int pw = bat * 64 + win;
  double* partG = (double*)(ws + WS_PART);
  if (((const uint32_t*)(ws + WS_SKIP))[win]) { if (tid == 0) partG[t] = 0.0; return; }
  const int M    = (int)((const uint32_t*)(ws + WS_M))[t];
  const int nlab = (int)((const uint32_t*)(ws + WS_NLAB))[pw];
  const uint32_t* msG = (const uint32_t*)(ws + WS_MSNAP) + t * 3;
  const uint16_t* snapG = (const uint16_t*)(ws + WS_SNAP) + (size_t)t * 3072;
  const int ms1 = (int)msG[0], ms2 = (int)msG[1], ms3 = (int)msG[2];
  if (tid == 0) Ssum = 0u;
  {
    const uint32_t* recG  = (const uint32_t*)(ws + WS_REC) + (size_t)t * NPIX;
    const float*    PwG   = (const float*)(ws + WS_PW)   + (size_t)pw * NPIX;
    const uint16_t* labG  = (const uint16_t*)(ws + WS_LAB)  + (size_t)pw * NPIX;
    const uint16_t* labDG = (const uint16_t*)(ws + WS_LABD) + (size_t)pw * NPIX;
    for (int m = tid; m < M; m += 256) { recW[m] = recG[m]; same[m] = 0u; totp[m] = 0u; }
    for (int p = tid; p < NPIX; p += 256) { Pw[p] = PwG[p]; lab[p] = labG[p]; labD[p] = labDG[p]; }
  }
  __syncthreads();

  // replay: waves split (row-group g, record-segment s). For nRows<=16 all 4
  // waves share rows 0..15 and each replays 1/4 of the records, initializing
  // its private C rows from the root snapshot at its segment start.
  const int wid = tid >> 6, wl = tid & 63;
  const int nRows = nlab + 1;               // + pseudo-row (all labeled pixels)
  for (int chb = 0; chb < nRows; chb += CROWS) {
    const int rowsHere = min(nRows - chb, CROWS);
    const int G = (rowsHere + 15) >> 4;     // 1..4 row groups this pass
    const int S = (G == 1) ? 4 : ((G == 2) ? 2 : 1);
    const int g = wid / S, s = wid % S;
    const int rowLo = chb + g * 16;
    int b0, b1;
    if (S == 4)      { b0 = (s == 0) ? 0 : (s == 1 ? ms1 : (s == 2 ? ms2 : ms3));
                       b1 = (s == 0) ? ms1 : (s == 1 ? ms2 : (s == 2 ? ms3 : M)); }
    else if (S == 2) { b0 = s ? ms2 : 0; b1 = s ? M : ms2; }
    else             { b0 = 0; b1 = M; }
    const bool active = (rowLo < nRows) && (b0 < b1);

    for (int i = tid; i < (CROWS * CNTW) / 2; i += 256) ((uint32_t*)u.cnt)[i] = 0u;
    __syncthreads();
    // init scatter: label counts per component root at segment start
    if (active) {
      const int rowHi = min(rowLo + 16, nRows);
      for (int p = wl; p < NPIX; p += 64) {
        uint16_t l = lab[p];
        if (!l) continue;
        int root = (s == 0) ? p : (int)snapG[(s - 1) * 1024 + p];
        int d = labD[l - 1];
        if (d) { int dl = d - 1; if (dl >= rowLo && dl < rowHi) cinc(u.cnt[wid * 16 + (dl - rowLo)], root); }
        if (nlab >= rowLo && nlab < rowHi) cinc(u.cnt[wid * 16 + (nlab - rowLo)], root);
      }
    }
    __syncthreads();
    // per-wave segment replay: R11-proven 1-deep run-cache body over [b0,b1)
    if (active && wl < 16) {
      int logical = rowLo + wl;
      if (logical < nRows) {
        const bool isP = (logical == nlab);
        uint16_t* C = u.cnt[wid * 16 + wl];
        int lastRa = -1; unsigned lastVal = 0;
        int pfr = -1; unsigned pfv = 0;
        unsigned w = recW[b0];
        int ra = (int)((w >> 11) & 1023u), rb = (int)(w >> 21);
        unsigned caL = C[ra], cbL = C[rb];
        for (int m = b0; m < b1; ++m) {
          int mn = (m + 1 < b1) ? m + 1 : m;
          unsigned wN = recW[mn];               // prefetch (stale set <= {lastRa, pfr})
          int raN = (int)((wN >> 11) & 1023u), rbN = (int)(wN >> 21);
          unsigned caN = C[raN], cbN = C[rbN];
          unsigned ca = (ra == lastRa) ? lastVal : ((ra == pfr) ? pfv : caL);
          unsigned cb = (rb == lastRa) ? lastVal : ((rb == pfr) ? pfv : cbL);
          int npfr = -1; unsigned npfv = 0;
          if (ra != lastRa) {
            if (lastRa >= 0) { C[lastRa] = (uint16_t)lastVal; npfr = lastRa; npfv = lastVal; }
            lastRa = ra; lastVal = ca;
          }
          if (cb) {
            if (isP) totp[m] = lastVal * cb;    // single writer per m, plain store
            else if (lastVal) atomicAdd(&same[m], lastVal * cb);
            lastVal += cb;
          }
          pfr = npfr; pfv = npfv;
          ra = raN; rb = rbN; caL = caN; cbL = cbN;
        }
      }
    }
    __syncthreads();
  }

  // normalization sum S and masked loss contribution
  unsigned mys = 0u;
  for (int m = tid; m < M; m += 256)
    mys += sign ? same[m] : (totp[m] - same[m]);
  atomicAdd(&Ssum, mys);
  __syncthreads();
  const unsigned S = Ssum;

  double part = 0.0;
  if (S > 0u) {
    for (int m = tid; m < M; m += 256) {
      unsigned np = sign ? same[m] : (totp[m] - same[m]);
      if (np == 0u) continue;
      int e = (int)(recW[m] & 2047u);
      int a, b; edge_nodes(e, a, b);
      int cls = (lab[a] ? 0 : 1) + (lab[b] ? 0 : 1);
      bool keep = sign ? (cls != 0)    // ewp[gt<20]=0 -> keep cls 1,2
                       : (cls == 0);   // ewn[gt>=10]=0 -> keep cls 0
      if (!keep) continue;
      double fa, fb;
      if (sign) {
        double da = 20.0 - (double)Pw[a], db = 20.0 - (double)Pw[b];
        fa = da * da; fb = db * db;
      } else {
        fa = (double)Pw[a] * (double)Pw[a];
        fb = (double)Pw[b] * (double)Pw[b];
      }
      part += (double)np * (fa + fb);
    }
  }
  u.red[tid] = part;     // cnt region dead (replay loop ended with barrier)
  __syncthreads();
  for (int st = 128; st > 0; st >>= 1) {
    if (tid < st) u.red[tid] += u.red[tid + st];
    __syncthreads();
  }
  if (tid == 0) partG[t] = (S > 0u) ? (u.red[0] / (double)S) : 0.0;
}

__global__ __launch_bounds__(256) void final_reduce(
    const double* __restrict__ part, float* __restrict__ out)
{
  __shared__ double r[256];
  int tdx = threadIdx.x;
  r[tdx] = part[tdx];
  __syncthreads();
  for (int st = 128; st > 0; st >>= 1) {
    if (tdx < st) r[tdx] += r[tdx + st];
    __syncthreads();
  }
  if (tdx == 0) out[0] = (float)r[0];
}

extern "C" void kernel_launch(void* const* d_in, const int* in_sizes, int n_in,
                              void* d_out, int out_size, void* d_ws, size_t ws_size,
                              hipStream_t stream) {
  const float* y_true = (const float*)d_in[0];
  const float* y_pred = (const float*)d_in[1];
  char* ws = (char*)d_ws;
  k1_prep<<<128, 256, 0, stream>>>(y_true, y_pred, ws);
  k2a_sort<<<256, 256, 0, stream>>>(ws);
  k2b_kruskal<<<256, 256, 0, stream>>>(ws);
  k2c_replay<<<256, 256, 0, stream>>>(ws);
  final_reduce<<<1, 256, 0, stream>>>((const double*)(ws + WS_PART), (float*)d_out);
}

// Round 18
// 285.858 us; speedup vs baseline: 1.1224x; 1.1224x over previous
//
#include <hip/hip_runtime.h>
#include <stdint.h>

#define NPIX 1024
#define NEDGE 1984
#define NSORT 2048
#define CROWS 64          // replay label rows (4 waves x 16)
#define CNTW (NPIX + 2)   // pad rows (even): replay lanes hit distinct banks; u32-aligned

// ---- d_ws layout (~4.73 MB) ----
#define WS_PART   0u          // f64[256]   per-task loss partials
#define WS_SKIP   2048u       // u32[64]    per-window skip flag
#define WS_NLAB   2304u       // u32[128]   per (bat,win) active-label count
#define WS_M      2816u       // u32[256]   per-task record count
#define WS_PW     4096u       // f32[128*1024]
#define WS_LAB    528384u     // u16[128*1024]  CC labels (min-pixel-id+1, 0=bg)
#define WS_LABD   790528u     // u16[128*1024]  active dense id+1 at min pixel
#define WS_REC    1052672u    // u32[256*1024]  packed e(11)|ra(10)|rb(10)
#define WS_MSNAP  3149824u    // u32[256*3]     record counts at snapshots
#define WS_SNAP   3153920u    // u16[256*3*1024] resolved roots at snapshots

__device__ __forceinline__ void edge_nodes(int e, int& a, int& b) {
  if (e < 992) { int r = e / 31; int c = e - r * 31; a = (r << 5) + c; b = a + 1; }
  else         { a = e - 992; b = a + 32; }
}

// u16 counter increment via aligned u32 atomic (halves < 65536: no carry)
__device__ __forceinline__ void cinc(uint16_t* row, int root) {
  uint32_t* w = (uint32_t*)(row + (root & ~1));
  atomicAdd(w, (root & 1) ? 0x10000u : 1u);
}

// path-halving find; concurrent halving writes are ancestor-monotone (safe)
__device__ __forceinline__ int uf_find(volatile uint32_t* par, int x) {
  int p = (int)par[x];
  while (p != x) {
    int gp = (int)par[p];
    par[x] = (uint32_t)gp;
    x = gp; p = (int)par[x];
  }
  return x;
}

// union-by-min with CAS hooking (Playne-Stephens style): final root = min id
__device__ __forceinline__ void uf_union(volatile uint32_t* par, int a, int b) {
  int ra = uf_find(par, a), rb = uf_find(par, b);
  while (ra != rb) {
    if (ra > rb) { int t2 = ra; ra = rb; rb = t2; }
    unsigned old = atomicCAS((unsigned*)(par + rb), (unsigned)rb, (unsigned)ra);
    if (old == (unsigned)rb) break;
    rb = uf_find(par, (int)old);
    ra = uf_find(par, ra);
  }
}

// ============ K1: load + skip predicate + union-find CC + label census ============
__global__ __launch_bounds__(256) void k1_prep(const float* __restrict__ y_true,
                                               const float* __restrict__ y_pred,
                                               char* __restrict__ ws) {
  __shared__ float    Pw[NPIX];
  __shared__ uint16_t lab[NPIX];
  __shared__ uint8_t  maskv[NPIX];
  __shared__ uint32_t lcnt[NPIX];
  __shared__ uint32_t par32[NPIX];
  __shared__ unsigned minP, maxP, minT, maxT;
  __shared__ int nl;
  const int tid = threadIdx.x, pw = blockIdx.x, bat = pw >> 6, win = pw & 63;
  const int wr = win >> 3, wc = win & 7;
  if (tid == 0) { minP = ~0u; maxP = 0u; minT = ~0u; maxT = 0u; nl = 0; }
  __syncthreads();
  {
    unsigned mnP = ~0u, mxP = 0u, mnT = ~0u, mxT = 0u;
    for (int i = tid; i < 2 * NPIX; i += 256) {
      int bb = i >> 10, p = i & (NPIX - 1);
      int r = p >> 5, c = p & 31;
      size_t g = ((size_t)(bb * 256 + wr * 32 + r)) * 256 + (size_t)(wc * 32 + c);
      float pv = y_pred[g], tv = y_true[g];
      unsigned pu = __float_as_uint(pv), tu = __float_as_uint(tv);
      mnP = min(mnP, pu); mxP = max(mxP, pu);
      mnT = min(mnT, tu); mxT = max(mxT, tu);
      if (bb == bat) {
        Pw[p] = pv; maskv[p] = (tv == 0.f) ? 1 : 0;
        par32[p] = (uint32_t)p;
        lcnt[p] = 0u;
      }
    }
    atomicMin(&minP, mnP); atomicMax(&maxP, mxP);   // valid: values >= 0
    atomicMin(&minT, mnT); atomicMax(&maxT, mxT);
  }
  __syncthreads();
  {
    float a = __uint_as_float(minP), b = __uint_as_float(maxP);
    float c2 = __uint_as_float(minT), d = __uint_as_float(maxT);
    int skip = (a == 1.f || b == 0.f || c2 == 1.f || d == 0.f) ? 1 : 0;
    if (tid == 0) ((uint32_t*)(ws + WS_SKIP))[win] = (uint32_t)skip;  // dup write: same value
    if (skip) return;
  }
  // ---- 8-connected CC: single edge pass, atomic union-by-min in LDS
  for (int p = tid; p < NPIX; p += 256) {
    if (!maskv[p]) continue;
    int r = p >> 5, c = p & 31;
    if (c < 31 && maskv[p + 1]) uf_union(par32, p, p + 1);
    if (r < 31) {
      if (maskv[p + 32])           uf_union(par32, p, p + 32);
      if (c < 31 && maskv[p + 33]) uf_union(par32, p, p + 33);
      if (c > 0  && maskv[p + 31]) uf_union(par32, p, p + 31);
    }
  }
  __syncthreads();
  // resolve roots (read-only walk; all unions complete) -> lab = min id + 1
  for (int p = tid; p < NPIX; p += 256) {
    uint16_t l = 0;
    if (maskv[p]) {
      int x = p, px = (int)par32[x];
      while (px != x) { x = px; px = (int)par32[x]; }
      l = (uint16_t)(x + 1);
    }
    lab[p] = l;
  }
  __syncthreads();
  for (int p = tid; p < NPIX; p += 256)
    if (maskv[p]) atomicAdd(&lcnt[lab[p] - 1], 1u);
  __syncthreads();
  uint16_t* labDG = (uint16_t*)(ws + WS_LABD) + (size_t)pw * NPIX;
  for (int p = tid; p < NPIX; p += 256) {
    uint16_t v = 0;
    if (maskv[p] && lab[p] == (uint16_t)(p + 1) && lcnt[p] >= 2u)
      v = (uint16_t)(atomicAdd(&nl, 1) + 1);
    labDG[p] = v;
  }
  __syncthreads();
  float*    PwG  = (float*)(ws + WS_PW)  + (size_t)pw * NPIX;
  uint16_t* labG = (uint16_t*)(ws + WS_LAB) + (size_t)pw * NPIX;
  for (int p = tid; p < NPIX; p += 256) { PwG[p] = Pw[p]; labG[p] = lab[p]; }
  if (tid == 0) ((uint32_t*)(ws + WS_NLAB))[pw] = (uint32_t)nl;
}

// ============ K2ab: keys + bitonic sort + register-UF Kruskal (fused; sorted
// keys stay in LDS -> no ordG round-trip). Serial core = R16 branchless. ======
__global__ __launch_bounds__(256) void k2ab_sortkruskal(char* __restrict__ ws) {
  __shared__ unsigned long long keys[NSORT];   // 16 KB (sorted edge order)
  __shared__ float    Pw[NPIX];
  __shared__ uint16_t lab[NPIX];
  __shared__ uint16_t par[NPIX];
  const int tid = threadIdx.x, t = blockIdx.x;
  const int sign = t & 1, win = (t >> 1) & 63, bat = t >> 7;
  const int pw = bat * 64 + win;
  uint32_t* MG = (uint32_t*)(ws + WS_M);
  uint32_t* msW = (uint32_t*)(ws + WS_MSNAP) + t * 3;
  if (((const uint32_t*)(ws + WS_SKIP))[win]) { if (tid == 0) MG[t] = 0u; return; }
  const float*    PwG  = (const float*)(ws + WS_PW)  + (size_t)pw * NPIX;
  const uint16_t* labG = (const uint16_t*)(ws + WS_LAB) + (size_t)pw * NPIX;
  for (int p = tid; p < NPIX; p += 256) {
    Pw[p] = PwG[p]; lab[p] = labG[p]; par[p] = (uint16_t)p;
  }
  __syncthreads();
  for (int e = tid; e < NSORT; e += 256) {
    if (e < NEDGE) {
      int a, b; edge_nodes(e, a, b);
      int cls = (lab[a] ? 0 : 1) + (lab[b] ? 0 : 1);
      float cost = Pw[a] + Pw[b];
      if (sign == 0) { if (cls == 2) cost = 20.0f; }   // costs_n[gt>20]=20
      else           { if (cls == 0) cost = 0.0f;  }   // costs_p[gt<10]=0
      keys[e] = (((unsigned long long)(__float_as_uint(cost) ^ 0xFFFFFFFFu)) << 32)
                | (unsigned long long)(unsigned)e;
    } else keys[e] = ~0ull;
  }
  __syncthreads();
  // register-fused bitonic (proven R7-R16)
  {
    unsigned long long x[8];
    const int baseI = tid * 8;
    #pragma unroll
    for (int v = 0; v < 8; ++v) x[v] = keys[baseI + v];
    #pragma unroll
    for (int kk = 2; kk <= 8; kk <<= 1) {
      #pragma unroll
      for (int j = kk >> 1; j > 0; j >>= 1) {
        #pragma unroll
        for (int v = 0; v < 8; ++v) {
          int p = v ^ j;
          if (p > v) {
            bool asc = (((baseI + v) & kk) == 0);
            unsigned long long A = x[v], B = x[p];
            if ((A > B) == asc) { x[v] = B; x[p] = A; }
          }
        }
      }
    }
    #pragma unroll
    for (int v = 0; v < 8; ++v) keys[baseI + v] = x[v];
  }
  for (int k = 16; k <= NSORT; k <<= 1) {
    for (int j = k >> 1; j >= 8; j >>= 1) {
      __syncthreads();
      for (int q = tid; q < NSORT / 2; q += 256) {
        int i = ((q & ~(j - 1)) << 1) | (q & (j - 1));
        int p = i + j;
        bool asc = ((i & k) == 0);
        unsigned long long A = keys[i], B = keys[p];
        if ((A > B) == asc) { keys[i] = B; keys[p] = A; }
      }
    }
    __syncthreads();
    {
      unsigned long long x[8];
      const int baseI = tid * 8;
      const bool asc = ((baseI & k) == 0);
      #pragma unroll
      for (int v = 0; v < 8; ++v) x[v] = keys[baseI + v];
      #pragma unroll
      for (int j = 4; j > 0; j >>= 1) {
        #pragma unroll
        for (int v = 0; v < 8; ++v) {
          int p = v ^ j;
          if (p > v) {
            unsigned long long A = x[v], B = x[p];
            if ((A > B) == asc) { x[v] = B; x[p] = A; }
          }
        }
      }
      #pragma unroll
      for (int v = 0; v < 8; ++v) keys[baseI + v] = x[v];
    }
  }
  __syncthreads();
  // ---- wave-0 register-UF Kruskal, R16 branchless serial core; edges read
  // directly from sorted keys in LDS (low word; first NEDGE slots are real).
  // All cross-lane ops in wave-uniform control flow (CDNA exec-mask rule).
  if (tid < 64) {
    const int lane = tid;
    const uint32_t* keyLo = (const uint32_t*)keys;     // little-endian low word
    uint32_t* recG = (uint32_t*)(ws + WS_REC) + (size_t)t * NPIX;
    uint16_t* snapW = (uint16_t*)(ws + WS_SNAP) + (size_t)t * 3072;
    int mTotal = 0, nsnp = 0;
    for (int base = 0; base < NEDGE; base += 64) {
      unsigned e = keyLo[(base + lane) * 2];
      int a, b; edge_nodes((int)e, a, b);
      int xa = a, xb = b;
      for (;;) {
        int pa = par[xa], pb = par[xb];    // read-only dual walk
        if (pa == xa && pb == xb) break;
        xa = pa; xb = pb;
      }
      int ra = xa, rb = xb;
      bool cand0 = (ra != rb);
      // consecutive-duplicate pre-filter (R15): identical batch-start pair on
      // the previous lane -> provably rejected later; drop up front.
      unsigned pkMe = (unsigned)ra | ((unsigned)rb << 10) | (cand0 ? (1u << 20) : 0u);
      unsigned pkPrev = (unsigned)__shfl((int)pkMe, (lane + 63) & 63, 64);
      bool cand = cand0 && !((lane > 0) && (pkPrev == pkMe));
      unsigned long long cm = __ballot(cand);
      int mb = 0;
      unsigned recP = 0u;                   // lane-mb packed (i | rA<<11 | rB<<21)
      while (cm) {
        int i = __ffsll((long long)cm) - 1;
        cm &= cm - 1;
        int rA = __builtin_amdgcn_readlane(ra, i);   // current root of a_i
        int rB = __builtin_amdgcn_readlane(rb, i);   // current root of b_i
        bool acc = (rA != rB);                        // uniform scalar
        unsigned pk = (unsigned)i | ((unsigned)rA << 11) | ((unsigned)rB << 21);
        if (acc && lane == mb) recP = pk;             // 1 cndmask (no branch emitted)
        ra = (ra == rB) ? rA : ra;                    // unconditional rename:
        rb = (rb == rB) ? rA : rb;                    //  no-op when rA==rB
        mb += acc ? 1 : 0;                            // SALU cselect
      }
      // end-of-batch: recover edge ids in parallel (one bpermute), write out
      unsigned eRec = (unsigned)__shfl((int)e, (int)(recP & 63u), 64);  // uniform flow
      if (lane < mb) {
        int rAo = (int)((recP >> 11) & 1023u);
        int rBo = (int)(recP >> 21);
        par[rBo] = (uint16_t)rAo;           // reference orientation par[rB]=rA
        recG[mTotal + lane] = (recP & 0xFFFFF800u) | eRec;
      }
      mTotal += mb;
      // batched pointer-jump compression (skip when chains are short)
      if (mb > 2 && (base + 64 < NEDGE)) {
        for (int pass = 0; pass < 2; ++pass) {
          uint16_t vv[16];
          #pragma unroll
          for (int j = 0; j < 16; ++j) vv[j] = par[j * 64 + lane];
          #pragma unroll
          for (int j = 0; j < 16; ++j) vv[j] = par[vv[j]];
          #pragma unroll
          for (int j = 0; j < 16; ++j) par[j * 64 + lane] = vv[j];
        }
      }
      // snapshot: fully-resolved roots once record count crosses s*256
      while (nsnp < 3 && mTotal >= 256 * (nsnp + 1)) {
        #pragma unroll
        for (int j = 0; j < 16; ++j) {
          int p = j * 64 + lane;
          int r = par[p], pr = par[r];
          while (pr != r) { r = pr; pr = par[r]; }
          snapW[nsnp * 1024 + p] = (uint16_t)r;
        }
        if (lane == 0) msW[nsnp] = (uint32_t)mTotal;
        ++nsnp;
      }
    }
    while (nsnp < 3) { if (lane == 0) msW[nsnp] = (uint32_t)mTotal; ++nsnp; }
    if (lane == 0) MG[t] = (uint32_t)mTotal;
  }
}

// ============ K2c: segment-parallel replay (4 waves over record segments) ============
__global__ __launch_bounds__(256) void k2c_replay(char* __restrict__ ws) {
  __shared__ union {
    uint16_t cnt[CROWS][CNTW];          // 131328 B (replay)
    double   red[256];                  //   2048 B (final reduction)
  } u;
  __shared__ float    Pw[NPIX];
  __shared__ uint16_t lab[NPIX];
  __shared__ uint16_t labD[NPIX];
  __shared__ uint32_t recW[NPIX];
  __shared__ uint32_t totp[NPIX];
  __shared__ uint32_t same[NPIX];
  __shared__ unsigned Ssum;
  const int tid = threadIdx.x, t = blockIdx.x;
  const int sign = t & 1, win = (t >> 1) & 63, bat = t >> 7;
  const int pw = bat * 64 + win;
  double* partG = (double*)(ws + WS_PART);
  if (((const uint32_t*)(ws + WS_SKIP))[win]) { if (tid == 0) partG[t] = 0.0; return; }
  const int M    = (int)((const uint32_t*)(ws + WS_M))[t];
  const int nlab = (int)((const uint32_t*)(ws + WS_NLAB))[pw];
  const uint32_t* msG = (const uint32_t*)(ws + WS_MSNAP) + t * 3;
  const uint16_t* snapG = (const uint16_t*)(ws + WS_SNAP) + (size_t)t * 3072;
  const int ms1 = (int)msG[0], ms2 = (int)msG[1], ms3 = (int)msG[2];
  if (tid == 0) Ssum = 0u;
  {
    const uint32_t* recG  = (const uint32_t*)(ws + WS_REC) + (size_t)t * NPIX;
    const float*    PwG   = (const float*)(ws + WS_PW)   + (size_t)pw * NPIX;
    const uint16_t* labG  = (const uint16_t*)(ws + WS_LAB)  + (size_t)pw * NPIX;
    const uint16_t* labDG = (const uint16_t*)(ws + WS_LABD) + (size_t)pw * NPIX;
    for (int m = tid; m < M; m += 256) { recW[m] = recG[m]; same[m] = 0u; totp[m] = 0u; }
    for (int p = tid; p < NPIX; p += 256) { Pw[p] = PwG[p]; lab[p] = labG[p]; labD[p] = labDG[p]; }
  }
  __syncthreads();

  // replay: waves split (row-group g, record-segment s). For nRows<=16 all 4
  // waves share rows 0..15 and each replays 1/4 of the records, initializing
  // its private C rows from the root snapshot at its segment start.
  const int wid = tid >> 6, wl = tid & 63;
  const int nRows = nlab + 1;               // + pseudo-row (all labeled pixels)
  for (int chb = 0; chb < nRows; chb += CROWS) {
    const int rowsHere = min(nRows - chb, CROWS);
    const int G = (rowsHere + 15) >> 4;     // 1..4 row groups this pass
    const int S = (G == 1) ? 4 : ((G == 2) ? 2 : 1);
    const int g = wid / S, s = wid % S;
    const int rowLo = chb + g * 16;
    int b0, b1;
    if (S == 4)      { b0 = (s == 0) ? 0 : (s == 1 ? ms1 : (s == 2 ? ms2 : ms3));
                       b1 = (s == 0) ? ms1 : (s == 1 ? ms2 : (s == 2 ? ms3 : M)); }
    else if (S == 2) { b0 = s ? ms2 : 0; b1 = s ? M : ms2; }
    else             { b0 = 0; b1 = M; }
    const bool active = (rowLo < nRows) && (b0 < b1);

    for (int i = tid; i < (CROWS * CNTW) / 2; i += 256) ((uint32_t*)u.cnt)[i] = 0u;
    __syncthreads();
    // init scatter: label counts per component root at segment start
    if (active) {
      const int rowHi = min(rowLo + 16, nRows);
      for (int p = wl; p < NPIX; p += 64) {
        uint16_t l = lab[p];
        if (!l) continue;
        int root = (s == 0) ? p : (int)snapG[(s - 1) * 1024 + p];
        int d = labD[l - 1];
        if (d) { int dl = d - 1; if (dl >= rowLo && dl < rowHi) cinc(u.cnt[wid * 16 + (dl - rowLo)], root); }
        if (nlab >= rowLo && nlab < rowHi) cinc(u.cnt[wid * 16 + (nlab - rowLo)], root);
      }
    }
    __syncthreads();
    // per-wave segment replay: R11-proven 1-deep run-cache body over [b0,b1)
    if (active && wl < 16) {
      int logical = rowLo + wl;
      if (logical < nRows) {
        const bool isP = (logical == nlab);
        uint16_t* C = u.cnt[wid * 16 + wl];
        int lastRa = -1; unsigned lastVal = 0;
        int pfr = -1; unsigned pfv = 0;
        unsigned w = recW[b0];
        int ra = (int)((w >> 11) & 1023u), rb = (int)(w >> 21);
        unsigned caL = C[ra], cbL = C[rb];
        for (int m = b0; m < b1; ++m) {
          int mn = (m + 1 < b1) ? m + 1 : m;
          unsigned wN = recW[mn];               // prefetch (stale set <= {lastRa, pfr})
          int raN = (int)((wN >> 11) & 1023u), rbN = (int)(wN >> 21);
          unsigned caN = C[raN], cbN = C[rbN];
          unsigned ca = (ra == lastRa) ? lastVal : ((ra == pfr) ? pfv : caL);
          unsigned cb = (rb == lastRa) ? lastVal : ((rb == pfr) ? pfv : cbL);
          int npfr = -1; unsigned npfv = 0;
          if (ra != lastRa) {
            if (lastRa >= 0) { C[lastRa] = (uint16_t)lastVal; npfr = lastRa; npfv = lastVal; }
            lastRa = ra; lastVal = ca;
          }
          if (cb) {
            if (isP) totp[m] = lastVal * cb;    // single writer per m, plain store
            else if (lastVal) atomicAdd(&same[m], lastVal * cb);
            lastVal += cb;
          }
          pfr = npfr; pfv = npfv;
          ra = raN; rb = rbN; caL = caN; cbL = cbN;
        }
      }
    }
    __syncthreads();
  }

  // normalization sum S and masked loss contribution
  unsigned mys = 0u;
  for (int m = tid; m < M; m += 256)
    mys += sign ? same[m] : (totp[m] - same[m]);
  atomicAdd(&Ssum, mys);
  __syncthreads();
  const unsigned S = Ssum;

  double part = 0.0;
  if (S > 0u) {
    for (int m = tid; m < M; m += 256) {
      unsigned np = sign ? same[m] : (totp[m] - same[m]);
      if (np == 0u) continue;
      int e = (int)(recW[m] & 2047u);
      int a, b; edge_nodes(e, a, b);
      int cls = (lab[a] ? 0 : 1) + (lab[b] ? 0 : 1);
      bool keep = sign ? (cls != 0)    // ewp[gt<20]=0 -> keep cls 1,2
                       : (cls == 0);   // ewn[gt>=10]=0 -> keep cls 0
      if (!keep) continue;
      double fa, fb;
      if (sign) {
        double da = 20.0 - (double)Pw[a], db = 20.0 - (double)Pw[b];
        fa = da * da; fb = db * db;
      } else {
        fa = (double)Pw[a] * (double)Pw[a];
        fb = (double)Pw[b] * (double)Pw[b];
      }
      part += (double)np * (fa + fb);
    }
  }
  u.red[tid] = part;     // cnt region dead (replay loop ended with barrier)
  __syncthreads();
  for (int st = 128; st > 0; st >>= 1) {
    if (tid < st) u.red[tid] += u.red[tid + st];
    __syncthreads();
  }
  if (tid == 0) partG[t] = (S > 0u) ? (u.red[0] / (double)S) : 0.0;
}

__global__ __launch_bounds__(256) void final_reduce(
    const double* __restrict__ part, float* __restrict__ out)
{
  __shared__ double r[256];
  int tdx = threadIdx.x;
  r[tdx] = part[tdx];
  __syncthreads();
  for (int st = 128; st > 0; st >>= 1) {
    if (tdx < st) r[tdx] += r[tdx + st];
    __syncthreads();
  }
  if (tdx == 0) out[0] = (float)r[0];
}

extern "C" void kernel_launch(void* const* d_in, const int* in_sizes, int n_in,
                              void* d_out, int out_size, void* d_ws, size_t ws_size,
                              hipStream_t stream) {
  const float* y_true = (const float*)d_in[0];
  const float* y_pred = (const float*)d_in[1];
  char* ws = (char*)d_ws;
  k1_prep<<<128, 256, 0, stream>>>(y_true, y_pred, ws);
  k2ab_sortkruskal<<<256, 256, 0, stream>>>(ws);
  k2c_replay<<<256, 256, 0, stream>>>(ws);
  final_reduce<<<1, 256, 0, stream>>>((const double*)(ws + WS_PART), (float*)d_out);
}

// Round 19
// 272.553 us; speedup vs baseline: 1.1772x; 1.0488x over previous
//
#include <hip/hip_runtime.h>
#include <stdint.h>

#define NPIX 1024
#define NEDGE 1984
#define NSORT 2048
#define CROWS 64          // replay label rows (4 waves x 16)
#define CNTW (NPIX + 2)   // pad rows (even): replay lanes hit distinct banks; u32-aligned

__device__ __forceinline__ void edge_nodes(int e, int& a, int& b) {
  if (e < 992) { int r = e / 31; int c = e - r * 31; a = (r << 5) + c; b = a + 1; }
  else         { a = e - 992; b = a + 32; }
}

// u16 counter increment via aligned u32 atomic (halves < 65536: no carry)
__device__ __forceinline__ void cinc(uint16_t* row, int root) {
  uint32_t* w = (uint32_t*)(row + (root & ~1));
  atomicAdd(w, (root & 1) ? 0x10000u : 1u);
}

// ============ MEGA: prep + sort + Kruskal + replay + epilogue, one task/block ============
struct SMem {
  union {
    uint16_t cnt[CROWS][CNTW];            // 131328 B (replay phase)
    struct {                              // sort + kruskal phase
      unsigned long long keys[NSORT];     // 16384 B
      uint16_t par[NPIX];                 //  2048 B
    } sk;
    struct {                              // prep phase
      uint32_t par32[NPIX];               //  4096 B
      uint32_t lcnt[NPIX];                //  4096 B
      uint8_t  maskv[NPIX];               //  1024 B
    } pp;
    double red[256];                      //  2048 B (final block reduction)
  } u;
  // persistent across phases:
  float    Pw[NPIX];          //  4096 B
  uint16_t lab[NPIX];         //  2048 B  CC labels (min-pixel-id+1, 0=bg)
  uint16_t labD[NPIX];        //  2048 B  active dense id+1 at min pixel
  uint32_t recW[NPIX];        //  4096 B  packed e(11)|ra(10)|rb(10)
  uint32_t totp[NPIX];        //  4096 B
  uint32_t same[NPIX];        //  4096 B
  uint16_t snapL[3][NPIX];    //  6144 B  resolved roots at snapshots
  unsigned minP, maxP, minT, maxT, Ssum;
  int nl, Msh, ms[3];
};                            // ~158.1 KB total

__global__ __launch_bounds__(256) void mega(const float* __restrict__ y_true,
                                            const float* __restrict__ y_pred,
                                            double* __restrict__ partG) {
  __shared__ SMem s;
  const int tid = threadIdx.x, t = blockIdx.x;
  const int sign = t & 1, win = (t >> 1) & 63, bat = t >> 7;
  const int wr = win >> 3, wc = win & 7;
  if (tid == 0) { s.minP = ~0u; s.maxP = 0u; s.minT = ~0u; s.maxT = 0u;
                  s.nl = 0; s.Msh = 0; s.Ssum = 0u; }
  __syncthreads();

  // ---- phase P: load window (both batches for skip predicate) + mask init
  {
    unsigned mnP = ~0u, mxP = 0u, mnT = ~0u, mxT = 0u;
    for (int i = tid; i < 2 * NPIX; i += 256) {
      int bb = i >> 10, p = i & (NPIX - 1);
      int r = p >> 5, c = p & 31;
      size_t g = ((size_t)(bb * 256 + wr * 32 + r)) * 256 + (size_t)(wc * 32 + c);
      float pv = y_pred[g], tv = y_true[g];
      unsigned pu = __float_as_uint(pv), tu = __float_as_uint(tv);
      mnP = min(mnP, pu); mxP = max(mxP, pu);
      mnT = min(mnT, tu); mxT = max(mxT, tu);
      if (bb == bat) {
        s.Pw[p] = pv; s.u.pp.maskv[p] = (tv == 0.f) ? 1 : 0;
        s.u.pp.par32[p] = (uint32_t)p;
        s.u.pp.lcnt[p] = 0u;
      }
    }
    atomicMin(&s.minP, mnP); atomicMax(&s.maxP, mxP);   // valid: values >= 0
    atomicMin(&s.minT, mnT); atomicMax(&s.maxT, mxT);
  }
  __syncthreads();
  {
    float a = __uint_as_float(s.minP), b = __uint_as_float(s.maxP);
    float c2 = __uint_as_float(s.minT), d = __uint_as_float(s.maxT);
    if (a == 1.f || b == 0.f || c2 == 1.f || d == 0.f) {
      if (tid == 0) partG[t] = 0.0;
      return;                                   // uniform across block
    }
  }
  // ---- 8-connected CC: single edge pass, atomic union-by-min in LDS (R14-proven)
  {
    volatile uint32_t* par32 = (volatile uint32_t*)s.u.pp.par32;
    uint8_t* maskv = s.u.pp.maskv;
    for (int p = tid; p < NPIX; p += 256) {
      if (!maskv[p]) continue;
      int r = p >> 5, c = p & 31;
      int nb[4]; int nn = 0;
      if (c < 31 && maskv[p + 1]) nb[nn++] = p + 1;
      if (r < 31) {
        if (maskv[p + 32])           nb[nn++] = p + 32;
        if (c < 31 && maskv[p + 33]) nb[nn++] = p + 33;
        if (c > 0  && maskv[p + 31]) nb[nn++] = p + 31;
      }
      for (int q = 0; q < nn; ++q) {
        // uf_union(par32, p, nb[q]) inlined
        int x = p, px = (int)par32[x];
        while (px != x) { int gp = (int)par32[px]; par32[x] = (uint32_t)gp; x = gp; px = (int)par32[x]; }
        int ra = x;
        x = nb[q]; px = (int)par32[x];
        while (px != x) { int gp = (int)par32[px]; par32[x] = (uint32_t)gp; x = gp; px = (int)par32[x]; }
        int rb = x;
        while (ra != rb) {
          if (ra > rb) { int t2 = ra; ra = rb; rb = t2; }
          unsigned old = atomicCAS((unsigned*)(par32 + rb), (unsigned)rb, (unsigned)ra);
          if (old == (unsigned)rb) break;
          // re-find both
          x = (int)old; px = (int)par32[x];
          while (px != x) { x = px; px = (int)par32[x]; }
          rb = x;
          x = ra; px = (int)par32[x];
          while (px != x) { x = px; px = (int)par32[x]; }
          ra = x;
        }
      }
    }
  }
  __syncthreads();
  // resolve roots -> lab = min id + 1 (read-only walk)
  for (int p = tid; p < NPIX; p += 256) {
    uint16_t l = 0;
    if (s.u.pp.maskv[p]) {
      int x = p, px = (int)s.u.pp.par32[x];
      while (px != x) { x = px; px = (int)s.u.pp.par32[x]; }
      l = (uint16_t)(x + 1);
    }
    s.lab[p] = l;
  }
  __syncthreads();
  for (int p = tid; p < NPIX; p += 256)
    if (s.lab[p]) atomicAdd(&s.u.pp.lcnt[s.lab[p] - 1], 1u);
  __syncthreads();
  for (int p = tid; p < NPIX; p += 256) {
    uint16_t v = 0;
    if (s.lab[p] && s.lab[p] == (uint16_t)(p + 1) && s.u.pp.lcnt[p] >= 2u)
      v = (uint16_t)(atomicAdd(&s.nl, 1) + 1);
    s.labD[p] = v;
  }
  for (int p = tid; p < NPIX; p += 256) { s.same[p] = 0u; s.totp[p] = 0u; }
  __syncthreads();
  const int nlab = s.nl;

  // ---- phase S: edge keys + register-fused bitonic (R18-proven; pp region dead)
  for (int e = tid; e < NSORT; e += 256) {
    if (e < NEDGE) {
      int a, b; edge_nodes(e, a, b);
      int cls = (s.lab[a] ? 0 : 1) + (s.lab[b] ? 0 : 1);
      float cost = s.Pw[a] + s.Pw[b];
      if (sign == 0) { if (cls == 2) cost = 20.0f; }   // costs_n[gt>20]=20
      else           { if (cls == 0) cost = 0.0f;  }   // costs_p[gt<10]=0
      s.u.sk.keys[e] = (((unsigned long long)(__float_as_uint(cost) ^ 0xFFFFFFFFu)) << 32)
                       | (unsigned long long)(unsigned)e;
    } else s.u.sk.keys[e] = ~0ull;
  }
  for (int p = tid; p < NPIX; p += 256) s.u.sk.par[p] = (uint16_t)p;
  __syncthreads();
  {
    unsigned long long x[8];
    const int baseI = tid * 8;
    #pragma unroll
    for (int v = 0; v < 8; ++v) x[v] = s.u.sk.keys[baseI + v];
    #pragma unroll
    for (int kk = 2; kk <= 8; kk <<= 1) {
      #pragma unroll
      for (int j = kk >> 1; j > 0; j >>= 1) {
        #pragma unroll
        for (int v = 0; v < 8; ++v) {
          int p = v ^ j;
          if (p > v) {
            bool asc = (((baseI + v) & kk) == 0);
            unsigned long long A = x[v], B = x[p];
            if ((A > B) == asc) { x[v] = B; x[p] = A; }
          }
        }
      }
    }
    #pragma unroll
    for (int v = 0; v < 8; ++v) s.u.sk.keys[baseI + v] = x[v];
  }
  for (int k = 16; k <= NSORT; k <<= 1) {
    for (int j = k >> 1; j >= 8; j >>= 1) {
      __syncthreads();
      for (int q = tid; q < NSORT / 2; q += 256) {
        int i = ((q & ~(j - 1)) << 1) | (q & (j - 1));
        int p = i + j;
        bool asc = ((i & k) == 0);
        unsigned long long A = s.u.sk.keys[i], B = s.u.sk.keys[p];
        if ((A > B) == asc) { s.u.sk.keys[i] = B; s.u.sk.keys[p] = A; }
      }
    }
    __syncthreads();
    {
      unsigned long long x[8];
      const int baseI = tid * 8;
      const bool asc = ((baseI & k) == 0);
      #pragma unroll
      for (int v = 0; v < 8; ++v) x[v] = s.u.sk.keys[baseI + v];
      #pragma unroll
      for (int j = 4; j > 0; j >>= 1) {
        #pragma unroll
        for (int v = 0; v < 8; ++v) {
          int p = v ^ j;
          if (p > v) {
            unsigned long long A = x[v], B = x[p];
            if ((A > B) == asc) { x[v] = B; x[p] = A; }
          }
        }
      }
      #pragma unroll
      for (int v = 0; v < 8; ++v) s.u.sk.keys[baseI + v] = x[v];
    }
  }
  __syncthreads();

  // ---- phase K: wave-0 register-UF Kruskal (R16 branchless core; R18 LDS feed)
  if (tid < 64) {
    const int lane = tid;
    const uint32_t* keyLo = (const uint32_t*)s.u.sk.keys;   // little-endian low word
    uint16_t* par = s.u.sk.par;
    int mTotal = 0, nsnp = 0;
    for (int base = 0; base < NEDGE; base += 64) {
      unsigned e = keyLo[(base + lane) * 2];
      int a, b; edge_nodes((int)e, a, b);
      int xa = a, xb = b;
      for (;;) {
        int pa = par[xa], pb = par[xb];    // read-only dual walk
        if (pa == xa && pb == xb) break;
        xa = pa; xb = pb;
      }
      int ra = xa, rb = xb;
      bool cand0 = (ra != rb);
      // consecutive-duplicate pre-filter (R15)
      unsigned pkMe = (unsigned)ra | ((unsigned)rb << 10) | (cand0 ? (1u << 20) : 0u);
      unsigned pkPrev = (unsigned)__shfl((int)pkMe, (lane + 63) & 63, 64);
      bool cand = cand0 && !((lane > 0) && (pkPrev == pkMe));
      unsigned long long cm = __ballot(cand);
      int mb = 0;
      unsigned recP = 0u;                   // lane-mb packed (i | rA<<11 | rB<<21)
      while (cm) {
        int i = __ffsll((long long)cm) - 1;
        cm &= cm - 1;
        int rA = __builtin_amdgcn_readlane(ra, i);
        int rB = __builtin_amdgcn_readlane(rb, i);
        bool acc = (rA != rB);                        // uniform scalar
        unsigned pk = (unsigned)i | ((unsigned)rA << 11) | ((unsigned)rB << 21);
        if (acc && lane == mb) recP = pk;
        ra = (ra == rB) ? rA : ra;                    // unconditional rename
        rb = (rb == rB) ? rA : rb;
        mb += acc ? 1 : 0;
      }
      unsigned eRec = (unsigned)__shfl((int)e, (int)(recP & 63u), 64);  // uniform flow
      if (lane < mb) {
        int rAo = (int)((recP >> 11) & 1023u);
        int rBo = (int)(recP >> 21);
        par[rBo] = (uint16_t)rAo;           // reference orientation par[rB]=rA
        s.recW[mTotal + lane] = (recP & 0xFFFFF800u) | eRec;
      }
      mTotal += mb;
      if (mb > 2 && (base + 64 < NEDGE)) {
        for (int pass = 0; pass < 2; ++pass) {
          uint16_t vv[16];
          #pragma unroll
          for (int j = 0; j < 16; ++j) vv[j] = par[j * 64 + lane];
          #pragma unroll
          for (int j = 0; j < 16; ++j) vv[j] = par[vv[j]];
          #pragma unroll
          for (int j = 0; j < 16; ++j) par[j * 64 + lane] = vv[j];
        }
      }
      while (nsnp < 3 && mTotal >= 256 * (nsnp + 1)) {
        #pragma unroll
        for (int j = 0; j < 16; ++j) {
          int p = j * 64 + lane;
          int r = par[p], pr = par[r];
          while (pr != r) { r = pr; pr = par[r]; }
          s.snapL[nsnp][p] = (uint16_t)r;
        }
        if (lane == 0) s.ms[nsnp] = mTotal;
        ++nsnp;
      }
    }
    while (nsnp < 3) { if (lane == 0) s.ms[nsnp] = mTotal; ++nsnp; }
    if (lane == 0) s.Msh = mTotal;
  }
  __syncthreads();
  const int M = s.Msh;
  const int ms1 = s.ms[0], ms2 = s.ms[1], ms3 = s.ms[2];

  // ---- phase R: segment-parallel replay (R13-proven; sk region dead -> cnt)
  const int wid = tid >> 6, wl = tid & 63;
  const int nRows = nlab + 1;               // + pseudo-row (all labeled pixels)
  for (int chb = 0; chb < nRows; chb += CROWS) {
    const int rowsHere = min(nRows - chb, CROWS);
    const int G = (rowsHere + 15) >> 4;     // 1..4 row groups this pass
    const int S = (G == 1) ? 4 : ((G == 2) ? 2 : 1);
    const int g = wid / S, sseg = wid % S;
    const int rowLo = chb + g * 16;
    int b0, b1;
    if (S == 4)      { b0 = (sseg == 0) ? 0 : (sseg == 1 ? ms1 : (sseg == 2 ? ms2 : ms3));
                       b1 = (sseg == 0) ? ms1 : (sseg == 1 ? ms2 : (sseg == 2 ? ms3 : M)); }
    else if (S == 2) { b0 = sseg ? ms2 : 0; b1 = sseg ? M : ms2; }
    else             { b0 = 0; b1 = M; }
    const bool active = (rowLo < nRows) && (b0 < b1);

    for (int i = tid; i < (CROWS * CNTW) / 2; i += 256) ((uint32_t*)s.u.cnt)[i] = 0u;
    __syncthreads();
    if (active) {
      const int rowHi = min(rowLo + 16, nRows);
      for (int p = wl; p < NPIX; p += 64) {
        uint16_t l = s.lab[p];
        if (!l) continue;
        int root = (sseg == 0) ? p : (int)s.snapL[sseg - 1][p];
        int d = s.labD[l - 1];
        if (d) { int dl = d - 1; if (dl >= rowLo && dl < rowHi) cinc(s.u.cnt[wid * 16 + (dl - rowLo)], root); }
        if (nlab >= rowLo && nlab < rowHi) cinc(s.u.cnt[wid * 16 + (nlab - rowLo)], root);
      }
    }
    __syncthreads();
    if (active && wl < 16) {
      int logical = rowLo + wl;
      if (logical < nRows) {
        const bool isP = (logical == nlab);
        uint16_t* C = s.u.cnt[wid * 16 + wl];
        int lastRa = -1; unsigned lastVal = 0;
        int pfr = -1; unsigned pfv = 0;
        unsigned w = s.recW[b0];
        int ra = (int)((w >> 11) & 1023u), rb = (int)(w >> 21);
        unsigned caL = C[ra], cbL = C[rb];
        for (int m = b0; m < b1; ++m) {
          int mn = (m + 1 < b1) ? m + 1 : m;
          unsigned wN = s.recW[mn];             // prefetch (stale set <= {lastRa, pfr})
          int raN = (int)((wN >> 11) & 1023u), rbN = (int)(wN >> 21);
          unsigned caN = C[raN], cbN = C[rbN];
          unsigned ca = (ra == lastRa) ? lastVal : ((ra == pfr) ? pfv : caL);
          unsigned cb = (rb == lastRa) ? lastVal : ((rb == pfr) ? pfv : cbL);
          int npfr = -1; unsigned npfv = 0;
          if (ra != lastRa) {
            if (lastRa >= 0) { C[lastRa] = (uint16_t)lastVal; npfr = lastRa; npfv = lastVal; }
            lastRa = ra; lastVal = ca;
          }
          if (cb) {
            if (isP) s.totp[m] = lastVal * cb;  // single writer per m, plain store
            else if (lastVal) atomicAdd(&s.same[m], lastVal * cb);
            lastVal += cb;
          }
          pfr = npfr; pfv = npfv;
          ra = raN; rb = rbN; caL = caN; cbL = cbN;
        }
      }
    }
    __syncthreads();
  }

  // ---- epilogue: normalization sum S and masked loss contribution
  unsigned mys = 0u;
  for (int m = tid; m < M; m += 256)
    mys += sign ? s.same[m] : (s.totp[m] - s.same[m]);
  atomicAdd(&s.Ssum, mys);
  __syncthreads();
  const unsigned S = s.Ssum;

  double part = 0.0;
  if (S > 0u) {
    for (int m = tid; m < M; m += 256) {
      unsigned np = sign ? s.same[m] : (s.totp[m] - s.same[m]);
      if (np == 0u) continue;
      int e = (int)(s.recW[m] & 2047u);
      int a, b; edge_nodes(e, a, b);
      int cls = (s.lab[a] ? 0 : 1) + (s.lab[b] ? 0 : 1);
      bool keep = sign ? (cls != 0)    // ewp[gt<20]=0 -> keep cls 1,2
                       : (cls == 0);   // ewn[gt>=10]=0 -> keep cls 0
      if (!keep) continue;
      double fa, fb;
      if (sign) {
        double da = 20.0 - (double)s.Pw[a], db = 20.0 - (double)s.Pw[b];
        fa = da * da; fb = db * db;
      } else {
        fa = (double)s.Pw[a] * (double)s.Pw[a];
        fb = (double)s.Pw[b] * (double)s.Pw[b];
      }
      part += (double)np * (fa + fb);
    }
  }
  s.u.red[tid] = part;     // cnt region dead (replay loop ended with barrier)
  __syncthreads();
  for (int st = 128; st > 0; st >>= 1) {
    if (tid < st) s.u.red[tid] += s.u.red[tid + st];
    __syncthreads();
  }
  if (tid == 0) partG[t] = (S > 0u) ? (s.u.red[0] / (double)S) : 0.0;
}

__global__ __launch_bounds__(256) void final_reduce(
    const double* __restrict__ part, float* __restrict__ out)
{
  __shared__ double r[256];
  int tdx = threadIdx.x;
  r[tdx] = part[tdx];
  __syncthreads();
  for (int st = 128; st > 0; st >>= 1) {
    if (tdx < st) r[tdx] += r[tdx + st];
    __syncthreads();
  }
  if (tdx == 0) out[0] = (float)r[0];
}

extern "C" void kernel_launch(void* const* d_in, const int* in_sizes, int n_in,
                              void* d_out, int out_size, void* d_ws, size_t ws_size,
                              hipStream_t stream) {
  const float* y_true = (const float*)d_in[0];
  const float* y_pred = (const float*)d_in[1];
  double* wsd = (double*)d_ws;            // 256 doubles of scratch
  mega<<<256, 256, 0, stream>>>(y_true, y_pred, wsd);
  final_reduce<<<1, 256, 0, stream>>>(wsd, (float*)d_out);
}